// Round 7
// baseline (7581.663 us; speedup 1.0000x reference)
//
#include <hip/hip_runtime.h>
#include <hip/hip_bf16.h>
#include <stdint.h>

#define NB 256
#define PERIOD 30

typedef __bf16  bf16x8 __attribute__((ext_vector_type(8)));
typedef float   f32x4  __attribute__((ext_vector_type(4)));
typedef unsigned int uint4v __attribute__((ext_vector_type(4)));

__device__ __forceinline__ float frcp(float x){ return __builtin_amdgcn_rcpf(x); }

// tanh(x) = 1 - 2/(exp(2x)+1)
__device__ __forceinline__ float fast_tanh(float x){
  float e = __expf(2.0f*x);
  return fmaf(-2.0f, frcp(e + 1.0f), 1.0f);
}

__device__ __forceinline__ unsigned int f2bfbits(float x){
  union { __hip_bfloat16 b; unsigned short u; } v;
  v.b = __float2bfloat16(x);          // RNE, matches XLA convert
  return (unsigned int)v.u;
}
__device__ __forceinline__ unsigned int pack2bf(float lo, float hi){
  return f2bfbits(lo) | (f2bfbits(hi) << 16);
}

// Threefry-2x32, 20 rounds, key = (0, 42)
__device__ __forceinline__ void threefry2x32_k42(uint32_t x0, uint32_t x1,
                                                 uint32_t& o0, uint32_t& o1){
  const uint32_t ks0 = 0u, ks1 = 42u, ks2 = 0u ^ 42u ^ 0x1BD11BDAu;
  x0 += ks0; x1 += ks1;
#define TFR(rot) { x0 += x1; x1 = (x1 << (rot)) | (x1 >> (32 - (rot))); x1 ^= x0; }
  TFR(13) TFR(15) TFR(26) TFR(6)
  x0 += ks1; x1 += ks2 + 1u;
  TFR(17) TFR(29) TFR(16) TFR(24)
  x0 += ks2; x1 += ks0 + 2u;
  TFR(13) TFR(15) TFR(26) TFR(6)
  x0 += ks0; x1 += ks1 + 3u;
  TFR(17) TFR(29) TFR(16) TFR(24)
  x0 += ks1; x1 += ks2 + 4u;
  TFR(13) TFR(15) TFR(26) TFR(6)
  x0 += ks2; x1 += ks0 + 5u;
#undef TFR
  o0 = x0; o1 = x1;
}

// Mirror jax.random.normal f32 (XLA erfinv polynomial)
__device__ __forceinline__ float normal_from_bits(uint32_t bits){
  float f = __uint_as_float((bits >> 9) | 0x3f800000u) - 1.0f;
  const float lo = -0.99999994f;
  float u = fmaf(f, 2.0f, lo);
  u = fmaxf(u, lo);
  float w = -log1pf(-u*u);
  float p;
  if (w < 5.0f){
    float ww = w - 2.5f;
    p = 2.81022636e-08f;
    p = fmaf(p, ww, 3.43273939e-07f);
    p = fmaf(p, ww, -3.5233877e-06f);
    p = fmaf(p, ww, -4.39150654e-06f);
    p = fmaf(p, ww, 0.00021858087f);
    p = fmaf(p, ww, -0.00125372503f);
    p = fmaf(p, ww, -0.00417768164f);
    p = fmaf(p, ww, 0.246640727f);
    p = fmaf(p, ww, 1.50140941f);
  } else {
    float ww = sqrtf(w) - 3.0f;
    p = -0.000200214257f;
    p = fmaf(p, ww, 0.000100950558f);
    p = fmaf(p, ww, 0.00134934322f);
    p = fmaf(p, ww, -0.00367342844f);
    p = fmaf(p, ww, 0.00573950773f);
    p = fmaf(p, ww, -0.0076224613f);
    p = fmaf(p, ww, 0.00943887047f);
    p = fmaf(p, ww, 1.00167406f);
    p = fmaf(p, ww, 2.83297682f);
  }
  return 1.41421356f * (p * u);
}

// stage one sample-tile's h/gA/gB columns (owners = lanes with grp==st)
__device__ __forceinline__ void stage_tile(char* buf, int st, int grp, int colL,
    const unsigned int* hp, const unsigned int* gap, const unsigned int* gbp){
  if (grp == st){
    const int rbase = colL * 128;
    const int sw = (colL & 7) << 4;
#pragma unroll
    for (int w = 0; w < 8; ++w){
      int off = rbase + ((w * 16) ^ sw);
      *(uint4v*)(buf + off)        = uint4v{hp[w*4],  hp[w*4+1],  hp[w*4+2],  hp[w*4+3]};
      *(uint4v*)(buf + 2048 + off) = uint4v{gap[w*4], gap[w*4+1], gap[w*4+2], gap[w*4+3]};
      *(uint4v*)(buf + 4096 + off) = uint4v{gbp[w*4], gbp[w*4+1], gbp[w*4+2], gbp[w*4+3]};
    }
  }
}

// MFMA net eval, swapped operands: C[n, sample].
// A = Wh^T (static frags bf), B = h/gA/gB sample columns (staged per tile).
// n-reduction: in-lane r/nt sums + shfl_xor(16,32) butterfly -> every lane
// holds the sum for sample st*16+(lane&15); lane keeps tile st==grp. No LDS
// scratch round-trip.
__device__ __forceinline__ void net_eval(
    float y2, float y3,
    const float* __restrict__ sIn,    // [64][4] f32 {w0a,w0b,b0,pad}
    char* sAw,                        // per-wave double buffer: 2 x [3][16][128B]
    const float* __restrict__ sBW,    // [3][32] (bh, wo) f32 pairs
    const bf16x8 (&bf)[3][2][2],      // Wh^T fragments (A operand)
    int colL, int grp,
    const float* bo_v,
    float& q1o, float& q2o, float& q3o,
    float& s11, float& s21, float& s31,
    float& s12, float& s22, float& s32)
{
  // ---- first layer (f32, per-lane = per-sample), pack bf16 columns ----
  unsigned int hp[32], gap[32], gbp[32];
#pragma unroll
  for (int d = 0; d < 32; ++d){
    float4 iA = ((const float4*)sIn)[2*d];
    float4 iB = ((const float4*)sIn)[2*d+1];
    float preA = fmaf(y2, iA.x, fmaf(y3, iA.y, iA.z));
    float preB = fmaf(y2, iB.x, fmaf(y3, iB.y, iB.z));
    float hA = fast_tanh(preA), hB = fast_tanh(preB);
    float uA = fmaf(-hA, hA, 1.0f), uB = fmaf(-hB, hB, 1.0f);
    hp[d]  = pack2bf(hA, hB);
    gap[d] = pack2bf(uA*iA.x, uB*iB.x);
    gbp[d] = pack2bf(uA*iA.y, uB*iB.y);
  }

  float qraw[3], Araw[3], Braw[3];
#pragma unroll
  for (int hd = 0; hd < 3; ++hd){ qraw[hd]=0.0f; Araw[hd]=0.0f; Braw[hd]=0.0f; }

  stage_tile(sAw, 0, grp, colL, hp, gap, gbp);

#pragma unroll 1
  for (int st = 0; st < 4; ++st){
    char* bufc = sAw + (st & 1) * 6144;

    // ---- B fragments for this tile (sample columns) ----
    bf16x8 afh[2], afg2[2], afg3[2];
#pragma unroll
    for (int kt = 0; kt < 2; ++kt){
      int off = colL*128 + ((kt*64 + grp*16) ^ ((colL & 7) << 4));
      afh[kt]  = *(const bf16x8*)(bufc + off);
      afg2[kt] = *(const bf16x8*)(bufc + 2048 + off);
      afg3[kt] = *(const bf16x8*)(bufc + 4096 + off);
    }

    // ---- prefetch next tile's staging (other buffer; overlaps MFMA) ----
    if (st < 3)
      stage_tile(sAw + ((st + 1) & 1) * 6144, st + 1, grp, colL, hp, gap, gbp);

#pragma unroll
    for (int hd = 0; hd < 3; ++hd){
      float qp = 0.0f, Ap = 0.0f, Bp = 0.0f;
#pragma unroll
      for (int nt = 0; nt < 2; ++nt){
        // (bh, wo) pairs for rows grp*4..+3 (broadcast within grp group)
        int pbase = (hd*32 + nt*16 + grp*4) >> 1;     // in f32x4 units
        f32x4 v0 = ((const f32x4*)sBW)[pbase];
        f32x4 v1 = ((const f32x4*)sBW)[pbase + 1];
        f32x4 cAT = {0,0,0,0}, cA2 = {0,0,0,0}, cA3 = {0,0,0,0};
#pragma unroll
        for (int kt = 0; kt < 2; ++kt){
          cAT = __builtin_amdgcn_mfma_f32_16x16x32_bf16(bf[hd][nt][kt], afh[kt],  cAT, 0, 0, 0);
          cA2 = __builtin_amdgcn_mfma_f32_16x16x32_bf16(bf[hd][nt][kt], afg2[kt], cA2, 0, 0, 0);
          cA3 = __builtin_amdgcn_mfma_f32_16x16x32_bf16(bf[hd][nt][kt], afg3[kt], cA3, 0, 0, 0);
        }
        float bhv[4] = {v0.x, v0.z, v1.x, v1.z};
        float wov[4] = {v0.y, v0.w, v1.y, v1.w};
#pragma unroll
        for (int r = 0; r < 4; ++r){
          float t  = fast_tanh(cAT[r] + bhv[r]);
          float dt = fmaf(-t, t, 1.0f);
          qp = fmaf(t, wov[r], qp);
          Ap = fmaf(dt * cA2[r], wov[r], Ap);
          Bp = fmaf(dt * cA3[r], wov[r], Bp);
        }
      }
      // full butterfly over the 4 row-groups -> all lanes get the n-sum
      qp += __shfl_xor(qp, 16, 64);  qp += __shfl_xor(qp, 32, 64);
      Ap += __shfl_xor(Ap, 16, 64);  Ap += __shfl_xor(Ap, 32, 64);
      Bp += __shfl_xor(Bp, 16, 64);  Bp += __shfl_xor(Bp, 32, 64);
      // lane keeps its own sample's tile
      bool keep = (st == grp);
      qraw[hd] = keep ? qp : qraw[hd];
      Araw[hd] = keep ? Ap : Araw[hd];
      Braw[hd] = keep ? Bp : Braw[hd];
    }
  }

  const float SIG = 0.03f;
  q1o = __expf(qraw[0] + bo_v[0]);
  q2o = __expf(qraw[1] + bo_v[1]);
  q3o = __expf(qraw[2] + bo_v[2]);
  s11 = SIG * Araw[0]; s21 = SIG * Araw[1]; s31 = SIG * Araw[2];
  s12 = SIG * Braw[0]; s22 = SIG * Braw[1]; s32 = SIG * Braw[2];
}

// NOTE: no min-waves __launch_bounds__ arg — it forces accumulator spills
// ((256,3)->210GB, (256,4)->42GB scratch writes). Natural allocation is clean.
__global__ __launch_bounds__(NB)
void sim_kernel(const float* __restrict__ Y,
  const float* __restrict__ W0,  const float* __restrict__ b0,
  const float* __restrict__ Wh1, const float* __restrict__ bh1,
  const float* __restrict__ Wo1, const float* __restrict__ bo1,
  const float* __restrict__ Wh2, const float* __restrict__ bh2,
  const float* __restrict__ Wo2, const float* __restrict__ bo2,
  const float* __restrict__ Wh3, const float* __restrict__ bh3,
  const float* __restrict__ Wo3, const float* __restrict__ bo3,
  float* __restrict__ out, int n)
{
  __shared__ __align__(16) char  sB[96 * 128];          // Wh^T bf16, swizzled
  __shared__ __align__(16) char  sA[4][2 * 3 * 16 * 128]; // per-wave dbuf (12KB)
  __shared__ __align__(16) float sBW[3 * 32 * 2];       // (bh, wo) pairs
  __shared__ __align__(16) float sIn[64 * 4];

  // ---- init B = Wh^T (bf16, swizzled) ----
  for (int e = threadIdx.x; e < 6144; e += NB){
    int hd = e >> 11, rem = e & 2047, j = rem >> 5, i = rem & 31;
    const float* W = (hd == 0) ? Wh1 : (hd == 1) ? Wh2 : Wh3;
    float v = W[j * 32 + i];
    int nrow = hd * 32 + i;
    int off = (nrow * 128 + j * 2) ^ ((nrow & 7) << 4);
    *(unsigned short*)(sB + off) = (unsigned short)f2bfbits(v);
  }
  if (threadIdx.x < 64){
    int j = threadIdx.x;
    sIn[j*4+0] = W0[j]; sIn[j*4+1] = W0[64+j]; sIn[j*4+2] = b0[j]; sIn[j*4+3] = 0.0f;
  }
  if (threadIdx.x < 96){
    int hd = threadIdx.x >> 5, row = threadIdx.x & 31;
    const float* BH = (hd == 0) ? bh1 : (hd == 1) ? bh2 : bh3;
    const float* WO = (hd == 0) ? Wo1 : (hd == 1) ? Wo2 : Wo3;
    sBW[threadIdx.x * 2 + 0] = BH[row];
    sBW[threadIdx.x * 2 + 1] = WO[row];
  }
  __syncthreads();

  const int wv   = threadIdx.x >> 6;
  const int lane = threadIdx.x & 63;
  const int colL = lane & 15;
  const int grp  = lane >> 4;
  char* sAw = &sA[wv][0];

  // ---- Wh^T fragments (A operand), loaded once ----
  bf16x8 bf[3][2][2];
#pragma unroll
  for (int hd = 0; hd < 3; ++hd)
#pragma unroll
    for (int nt = 0; nt < 2; ++nt)
#pragma unroll
      for (int kt = 0; kt < 2; ++kt){
        int nrow = hd*32 + nt*16 + colL;
        int off = nrow*128 + ((kt*64 + grp*16) ^ ((colL & 7) << 4));
        bf[hd][nt][kt] = *(const bf16x8*)(sB + off);
      }

  float bo_v[3] = {bo1[0], bo2[0], bo3[0]};

  const int gid = blockIdx.x * NB + threadIdx.x;
  const int ii  = (gid < n) ? gid : (n - 1);
  const float valid = (gid < n) ? 1.0f : 0.0f;

  const float2 yv = ((const float2*)Y)[ii];
  const float y2 = yv.x, y3 = yv.y;

  const float GAMMA = 1.2f, DT = 0.005f, SIGMA = 0.03f;
  const float KAPPA = 0.2f, YBAR = 2.0f, RHO = 0.03f, Bc = 1.0f, Cc = 0.1f;

  float q1,q2,q3,s11,s21,s31,s12,s22,s32;
  net_eval(y2, y3, sIn, sAw, sBW, bf, colL, grp, bo_v,
           q1,q2,q3,s11,s21,s31,s12,s22,s32);
  float Y2 = y2, Y3 = y3;
  float loss = 0.0f;

  for (int t = 0; t < PERIOD; ++t){
    // --- noise: threefry rollout, counter = flat index (bit-exact) ---
    uint32_t idx0 = 2u * ((uint32_t)t * (uint32_t)n + (uint32_t)ii);
    uint32_t a0, a1, c0, c1;
    threefry2x32_k42(0u, idx0,      a0, a1);
    threefry2x32_k42(0u, idx0 + 1u, c0, c1);
    float dZ1 = 0.070710678f * normal_from_bits(a0 ^ a1);
    float dZ2 = 0.070710678f * normal_from_bits(c0 ^ c1);

    // --- step math (mirror reference, f32) ---
    float Wt  = q1 + q2 + q3;
    float q1h = q1 / Wt;
    float q2h = q2 / Wt;
    float q3h = 1.0f - q1h - q2h;
    float q1sq = q1 * q1;
    float c   = Bc*q1 - Cc*q1sq + Y2 + Y3;
    float bq  = Bc*q1 - 2.0f*Cc*q1sq;
    float sc1 = fmaf(bq, s11, SIGMA);
    float sc2 = fmaf(bq, s12, SIGMA);
    float sW1 = q1*s11 + q2*s21 + q3*s31;
    float sW2 = q1*s12 + q2*s22 + q3*s32;
    float sJ1 = 6.0f * (sc1/c - sW1/Wt);
    float sJ2 = 6.0f * (sc2/c - sW2/Wt);
    float d11 = s11*s11 + s12*s12;
    float d12 = s11*s21 + s12*s22;
    float d13 = s11*s31 + s12*s32;
    float d22 = s21*s21 + s22*s22;
    float d23 = s21*s31 + s22*s32;
    float d33 = s31*s31 + s32*s32;
    const float oneMG = 1.0f - GAMMA;   // -0.2
    float p1 = GAMMA*(q1h*d11 + q2h*d12 + q3h*d13) - oneMG*(sJ1*s11 + sJ2*s12);
    float p2 = GAMMA*(q1h*d12 + q2h*d22 + q3h*d23) - oneMG*(sJ1*s21 + sJ2*s22);
    float p3 = GAMMA*(q1h*d13 + q2h*d23 + q3h*d33) - oneMG*(sJ1*s31 + sJ2*s32);
    float muY2 = KAPPA * (YBAR - Y2);
    float muY3 = KAPPA * (YBAR - Y3);
    float r = RHO + GAMMA*(bq*(p1 - (Bc - Cc*q1)) - Cc*q1sq*d11 + muY2 + muY3)/c
                  - 1.32f*(sc1*sc1 + sc2*sc2)/(c*c);
    r = r / (1.0f - GAMMA*bq/c);
    float mu1 = r + p1 - (Bc - Cc*q1);
    float mu2 = r + p2 - Y2/q2;
    float mu3 = r + p3 - Y3/q3;
    float q1n = q1 * (1.0f + mu1*DT + s11*dZ1 + s12*dZ2);
    float q2n = q2 * (1.0f + mu2*DT + s21*dZ1 + s22*dZ2);
    float q3n = q3 * (1.0f + mu3*DT + s31*dZ1 + s32*dZ2);
    float Y2n = Y2 + muY2*DT + SIGMA*dZ1;
    float Y3n = Y3 + muY3*DT + SIGMA*dZ2;

    float qt1, qt2, qt3;
    net_eval(Y2n, Y3n, sIn, sAw, sBW, bf, colL, grp, bo_v,
             qt1,qt2,qt3, s11,s21,s31,s12,s22,s32);

    float e1 = q1n - qt1, e2 = q2n - qt2, e3 = q3n - qt3;
    loss += e1*e1 + e2*e2 + e3*e3;

    q1 = q1n; q2 = q2n; q3 = q3n; Y2 = Y2n; Y3 = Y3n;
  }

  loss *= valid * (1.0f / ((float)15000000));   // / (n * PERIOD)

  // --- block reduction -> one atomic per block ---
#pragma unroll
  for (int off = 32; off > 0; off >>= 1)
    loss += __shfl_down(loss, off, 64);
  __shared__ float sred[NB / 64];
  if (lane == 0) sred[wv] = loss;
  __syncthreads();
  if (threadIdx.x == 0){
    float s = 0.0f;
#pragma unroll
    for (int w = 0; w < NB / 64; ++w) s += sred[w];
    atomicAdd(out, s);
  }
}

extern "C" void kernel_launch(void* const* d_in, const int* in_sizes, int n_in,
                              void* d_out, int out_size, void* d_ws, size_t ws_size,
                              hipStream_t stream)
{
  const float* Y   = (const float*)d_in[0];
  const float* W0  = (const float*)d_in[1];
  const float* b0  = (const float*)d_in[2];
  const float* Wh1 = (const float*)d_in[3];
  const float* bh1 = (const float*)d_in[4];
  const float* Wo1 = (const float*)d_in[5];
  const float* bo1 = (const float*)d_in[6];
  const float* Wh2 = (const float*)d_in[7];
  const float* bh2 = (const float*)d_in[8];
  const float* Wo2 = (const float*)d_in[9];
  const float* bo2 = (const float*)d_in[10];
  const float* Wh3 = (const float*)d_in[11];
  const float* bh3 = (const float*)d_in[12];
  const float* Wo3 = (const float*)d_in[13];
  const float* bo3 = (const float*)d_in[14];

  const int n = in_sizes[0] / 2;

  hipMemsetAsync(d_out, 0, sizeof(float), stream);

  const int grid = (n + NB - 1) / NB;
  sim_kernel<<<grid, NB, 0, stream>>>(Y,
      W0, b0, Wh1, bh1, Wo1, bo1, Wh2, bh2, Wo2, bo2, Wh3, bh3, Wo3, bo3,
      (float*)d_out, n);
}

// Round 8
// 6752.402 us; speedup vs baseline: 1.1228x; 1.1228x over previous
//
#include <hip/hip_runtime.h>
#include <hip/hip_bf16.h>
#include <stdint.h>

#define NB 256
#define PERIOD 30

typedef __bf16  bf16x8 __attribute__((ext_vector_type(8)));
typedef float   f32x4  __attribute__((ext_vector_type(4)));
typedef unsigned int uint4v __attribute__((ext_vector_type(4)));

__device__ __forceinline__ float frcp(float x){ return __builtin_amdgcn_rcpf(x); }

// tanh(x) = 1 - 2/(exp(2x)+1)
__device__ __forceinline__ float fast_tanh(float x){
  float e = __expf(2.0f*x);
  return fmaf(-2.0f, frcp(e + 1.0f), 1.0f);
}

__device__ __forceinline__ unsigned int f2bfbits(float x){
  union { __hip_bfloat16 b; unsigned short u; } v;
  v.b = __float2bfloat16(x);          // RNE, matches XLA convert
  return (unsigned int)v.u;
}
__device__ __forceinline__ unsigned int pack2bf(float lo, float hi){
  return f2bfbits(lo) | (f2bfbits(hi) << 16);
}

// Threefry-2x32, 20 rounds, key = (0, 42)
__device__ __forceinline__ void threefry2x32_k42(uint32_t x0, uint32_t x1,
                                                 uint32_t& o0, uint32_t& o1){
  const uint32_t ks0 = 0u, ks1 = 42u, ks2 = 0u ^ 42u ^ 0x1BD11BDAu;
  x0 += ks0; x1 += ks1;
#define TFR(rot) { x0 += x1; x1 = (x1 << (rot)) | (x1 >> (32 - (rot))); x1 ^= x0; }
  TFR(13) TFR(15) TFR(26) TFR(6)
  x0 += ks1; x1 += ks2 + 1u;
  TFR(17) TFR(29) TFR(16) TFR(24)
  x0 += ks2; x1 += ks0 + 2u;
  TFR(13) TFR(15) TFR(26) TFR(6)
  x0 += ks0; x1 += ks1 + 3u;
  TFR(17) TFR(29) TFR(16) TFR(24)
  x0 += ks1; x1 += ks2 + 4u;
  TFR(13) TFR(15) TFR(26) TFR(6)
  x0 += ks2; x1 += ks0 + 5u;
#undef TFR
  o0 = x0; o1 = x1;
}

// Mirror jax.random.normal f32 (XLA erfinv polynomial)
__device__ __forceinline__ float normal_from_bits(uint32_t bits){
  float f = __uint_as_float((bits >> 9) | 0x3f800000u) - 1.0f;
  const float lo = -0.99999994f;
  float u = fmaf(f, 2.0f, lo);
  u = fmaxf(u, lo);
  float w = -log1pf(-u*u);
  float p;
  if (w < 5.0f){
    float ww = w - 2.5f;
    p = 2.81022636e-08f;
    p = fmaf(p, ww, 3.43273939e-07f);
    p = fmaf(p, ww, -3.5233877e-06f);
    p = fmaf(p, ww, -4.39150654e-06f);
    p = fmaf(p, ww, 0.00021858087f);
    p = fmaf(p, ww, -0.00125372503f);
    p = fmaf(p, ww, -0.00417768164f);
    p = fmaf(p, ww, 0.246640727f);
    p = fmaf(p, ww, 1.50140941f);
  } else {
    float ww = sqrtf(w) - 3.0f;
    p = -0.000200214257f;
    p = fmaf(p, ww, 0.000100950558f);
    p = fmaf(p, ww, 0.00134934322f);
    p = fmaf(p, ww, -0.00367342844f);
    p = fmaf(p, ww, 0.00573950773f);
    p = fmaf(p, ww, -0.0076224613f);
    p = fmaf(p, ww, 0.00943887047f);
    p = fmaf(p, ww, 1.00167406f);
    p = fmaf(p, ww, 2.83297682f);
  }
  return 1.41421356f * (p * u);
}

// stage one sample-tile's h/gA/gB columns (owners = lanes with grp==st)
__device__ __forceinline__ void stage_tile(char* buf, int st, int grp, int colL,
    const unsigned int* hp, const unsigned int* gap, const unsigned int* gbp){
  if (grp == st){
    const int rbase = colL * 128;
    const int sw = (colL & 7) << 4;
#pragma unroll
    for (int w = 0; w < 8; ++w){
      int off = rbase + ((w * 16) ^ sw);
      *(uint4v*)(buf + off)        = uint4v{hp[w*4],  hp[w*4+1],  hp[w*4+2],  hp[w*4+3]};
      *(uint4v*)(buf + 2048 + off) = uint4v{gap[w*4], gap[w*4+1], gap[w*4+2], gap[w*4+3]};
      *(uint4v*)(buf + 4096 + off) = uint4v{gbp[w*4], gbp[w*4+1], gbp[w*4+2], gbp[w*4+3]};
    }
  }
}

// MFMA net eval, swapped operands: C[n, sample].
// A = Wh^T (read from LDS sB at point of use — NEVER hoist to long-lived
// registers: R7 did, allocator spilled them, every eval re-read scratch
// -> 5.6 GB FETCH. LDS is the register extension here).
// B = h/gA/gB sample columns (staged per tile, double-buffered).
// n-reduction: in-lane sums + shfl_xor(16,32) butterfly; lane keeps tile
// st==grp. No LDS scratch round-trip.
__device__ __forceinline__ void net_eval(
    float y2, float y3,
    const float* __restrict__ sIn,    // [64][4] f32 {w0a,w0b,b0,pad}
    char* sAw,                        // per-wave double buffer: 2 x [3][16][128B]
    const char* __restrict__ sBb,     // Wh^T bf16 swizzled [96][128B]
    const float* __restrict__ sBW,    // [3][32] (bh, wo) f32 pairs
    int colL, int grp,
    const float* bo_v,
    float& q1o, float& q2o, float& q3o,
    float& s11, float& s21, float& s31,
    float& s12, float& s22, float& s32)
{
  // ---- first layer (f32, per-lane = per-sample), pack bf16 columns ----
  unsigned int hp[32], gap[32], gbp[32];
#pragma unroll
  for (int d = 0; d < 32; ++d){
    float4 iA = ((const float4*)sIn)[2*d];
    float4 iB = ((const float4*)sIn)[2*d+1];
    float preA = fmaf(y2, iA.x, fmaf(y3, iA.y, iA.z));
    float preB = fmaf(y2, iB.x, fmaf(y3, iB.y, iB.z));
    float hA = fast_tanh(preA), hB = fast_tanh(preB);
    float uA = fmaf(-hA, hA, 1.0f), uB = fmaf(-hB, hB, 1.0f);
    hp[d]  = pack2bf(hA, hB);
    gap[d] = pack2bf(uA*iA.x, uB*iB.x);
    gbp[d] = pack2bf(uA*iA.y, uB*iB.y);
  }

  float qraw[3], Araw[3], Braw[3];
#pragma unroll
  for (int hd = 0; hd < 3; ++hd){ qraw[hd]=0.0f; Araw[hd]=0.0f; Braw[hd]=0.0f; }

  stage_tile(sAw, 0, grp, colL, hp, gap, gbp);

  const int bsw = (colL & 7) << 4;   // B-side swizzle key (row = colL)

#pragma unroll 1
  for (int st = 0; st < 4; ++st){
    char* bufc = sAw + (st & 1) * 6144;

    // ---- B fragments for this tile (sample columns) ----
    bf16x8 afh[2], afg2[2], afg3[2];
#pragma unroll
    for (int kt = 0; kt < 2; ++kt){
      int off = colL*128 + ((kt*64 + grp*16) ^ bsw);
      afh[kt]  = *(const bf16x8*)(bufc + off);
      afg2[kt] = *(const bf16x8*)(bufc + 2048 + off);
      afg3[kt] = *(const bf16x8*)(bufc + 4096 + off);
    }

    // ---- prefetch next tile's staging (other buffer; overlaps MFMA) ----
    if (st < 3)
      stage_tile(sAw + ((st + 1) & 1) * 6144, st + 1, grp, colL, hp, gap, gbp);

#pragma unroll
    for (int hd = 0; hd < 3; ++hd){
      float qp = 0.0f, Ap = 0.0f, Bp = 0.0f;
#pragma unroll
      for (int nt = 0; nt < 2; ++nt){
        // Wh^T fragments from LDS at point of use
        bf16x8 bfr[2];
#pragma unroll
        for (int kt = 0; kt < 2; ++kt){
          int nrow = hd*32 + nt*16 + colL;
          int off = nrow*128 + ((kt*64 + grp*16) ^ bsw);
          bfr[kt] = *(const bf16x8*)(sBb + off);
        }
        int pbase = (hd*32 + nt*16 + grp*4) >> 1;     // (bh,wo) pairs, f32x4 units
        f32x4 v0 = ((const f32x4*)sBW)[pbase];
        f32x4 v1 = ((const f32x4*)sBW)[pbase + 1];
        f32x4 cAT = {0,0,0,0}, cA2 = {0,0,0,0}, cA3 = {0,0,0,0};
#pragma unroll
        for (int kt = 0; kt < 2; ++kt){
          cAT = __builtin_amdgcn_mfma_f32_16x16x32_bf16(bfr[kt], afh[kt],  cAT, 0, 0, 0);
          cA2 = __builtin_amdgcn_mfma_f32_16x16x32_bf16(bfr[kt], afg2[kt], cA2, 0, 0, 0);
          cA3 = __builtin_amdgcn_mfma_f32_16x16x32_bf16(bfr[kt], afg3[kt], cA3, 0, 0, 0);
        }
        float bhv[4] = {v0.x, v0.z, v1.x, v1.z};
        float wov[4] = {v0.y, v0.w, v1.y, v1.w};
#pragma unroll
        for (int r = 0; r < 4; ++r){
          float t  = fast_tanh(cAT[r] + bhv[r]);
          float dt = fmaf(-t, t, 1.0f);
          qp = fmaf(t, wov[r], qp);
          Ap = fmaf(dt * cA2[r], wov[r], Ap);
          Bp = fmaf(dt * cA3[r], wov[r], Bp);
        }
      }
      // full butterfly over the 4 row-groups -> all lanes get the n-sum
      qp += __shfl_xor(qp, 16, 64);  qp += __shfl_xor(qp, 32, 64);
      Ap += __shfl_xor(Ap, 16, 64);  Ap += __shfl_xor(Ap, 32, 64);
      Bp += __shfl_xor(Bp, 16, 64);  Bp += __shfl_xor(Bp, 32, 64);
      // lane keeps its own sample's tile
      bool keep = (st == grp);
      qraw[hd] = keep ? qp : qraw[hd];
      Araw[hd] = keep ? Ap : Araw[hd];
      Braw[hd] = keep ? Bp : Braw[hd];
    }
  }

  const float SIG = 0.03f;
  q1o = __expf(qraw[0] + bo_v[0]);
  q2o = __expf(qraw[1] + bo_v[1]);
  q3o = __expf(qraw[2] + bo_v[2]);
  s11 = SIG * Araw[0]; s21 = SIG * Araw[1]; s31 = SIG * Araw[2];
  s12 = SIG * Braw[0]; s22 = SIG * Braw[1]; s32 = SIG * Braw[2];
}

// NOTE: no min-waves __launch_bounds__ arg — it forces accumulator spills
// ((256,3)->210GB, (256,4)->42GB scratch writes). Natural allocation is clean.
__global__ __launch_bounds__(NB)
void sim_kernel(const float* __restrict__ Y,
  const float* __restrict__ W0,  const float* __restrict__ b0,
  const float* __restrict__ Wh1, const float* __restrict__ bh1,
  const float* __restrict__ Wo1, const float* __restrict__ bo1,
  const float* __restrict__ Wh2, const float* __restrict__ bh2,
  const float* __restrict__ Wo2, const float* __restrict__ bo2,
  const float* __restrict__ Wh3, const float* __restrict__ bh3,
  const float* __restrict__ Wo3, const float* __restrict__ bo3,
  float* __restrict__ out, int n)
{
  __shared__ __align__(16) char  sB[96 * 128];            // Wh^T bf16, swizzled
  __shared__ __align__(16) char  sA[4][2 * 3 * 16 * 128]; // per-wave dbuf (12KB)
  __shared__ __align__(16) float sBW[3 * 32 * 2];         // (bh, wo) pairs
  __shared__ __align__(16) float sIn[64 * 4];

  // ---- init B = Wh^T (bf16, swizzled) ----
  for (int e = threadIdx.x; e < 6144; e += NB){
    int hd = e >> 11, rem = e & 2047, j = rem >> 5, i = rem & 31;
    const float* W = (hd == 0) ? Wh1 : (hd == 1) ? Wh2 : Wh3;
    float v = W[j * 32 + i];
    int nrow = hd * 32 + i;
    int off = (nrow * 128 + j * 2) ^ ((nrow & 7) << 4);
    *(unsigned short*)(sB + off) = (unsigned short)f2bfbits(v);
  }
  if (threadIdx.x < 64){
    int j = threadIdx.x;
    sIn[j*4+0] = W0[j]; sIn[j*4+1] = W0[64+j]; sIn[j*4+2] = b0[j]; sIn[j*4+3] = 0.0f;
  }
  if (threadIdx.x < 96){
    int hd = threadIdx.x >> 5, row = threadIdx.x & 31;
    const float* BH = (hd == 0) ? bh1 : (hd == 1) ? bh2 : bh3;
    const float* WO = (hd == 0) ? Wo1 : (hd == 1) ? Wo2 : Wo3;
    sBW[threadIdx.x * 2 + 0] = BH[row];
    sBW[threadIdx.x * 2 + 1] = WO[row];
  }
  __syncthreads();

  const int wv   = threadIdx.x >> 6;
  const int lane = threadIdx.x & 63;
  const int colL = lane & 15;
  const int grp  = lane >> 4;
  char* sAw = &sA[wv][0];

  float bo_v[3] = {bo1[0], bo2[0], bo3[0]};

  const int gid = blockIdx.x * NB + threadIdx.x;
  const int ii  = (gid < n) ? gid : (n - 1);
  const float valid = (gid < n) ? 1.0f : 0.0f;

  const float2 yv = ((const float2*)Y)[ii];
  const float y2 = yv.x, y3 = yv.y;

  const float GAMMA = 1.2f, DT = 0.005f, SIGMA = 0.03f;
  const float KAPPA = 0.2f, YBAR = 2.0f, RHO = 0.03f, Bc = 1.0f, Cc = 0.1f;

  float q1,q2,q3,s11,s21,s31,s12,s22,s32;
  net_eval(y2, y3, sIn, sAw, sB, sBW, colL, grp, bo_v,
           q1,q2,q3,s11,s21,s31,s12,s22,s32);
  float Y2 = y2, Y3 = y3;
  float loss = 0.0f;

  for (int t = 0; t < PERIOD; ++t){
    // --- noise: threefry rollout, counter = flat index (bit-exact) ---
    uint32_t idx0 = 2u * ((uint32_t)t * (uint32_t)n + (uint32_t)ii);
    uint32_t a0, a1, c0, c1;
    threefry2x32_k42(0u, idx0,      a0, a1);
    threefry2x32_k42(0u, idx0 + 1u, c0, c1);
    float dZ1 = 0.070710678f * normal_from_bits(a0 ^ a1);
    float dZ2 = 0.070710678f * normal_from_bits(c0 ^ c1);

    // --- step math (mirror reference, f32) ---
    float Wt  = q1 + q2 + q3;
    float q1h = q1 / Wt;
    float q2h = q2 / Wt;
    float q3h = 1.0f - q1h - q2h;
    float q1sq = q1 * q1;
    float c   = Bc*q1 - Cc*q1sq + Y2 + Y3;
    float bq  = Bc*q1 - 2.0f*Cc*q1sq;
    float sc1 = fmaf(bq, s11, SIGMA);
    float sc2 = fmaf(bq, s12, SIGMA);
    float sW1 = q1*s11 + q2*s21 + q3*s31;
    float sW2 = q1*s12 + q2*s22 + q3*s32;
    float sJ1 = 6.0f * (sc1/c - sW1/Wt);
    float sJ2 = 6.0f * (sc2/c - sW2/Wt);
    float d11 = s11*s11 + s12*s12;
    float d12 = s11*s21 + s12*s22;
    float d13 = s11*s31 + s12*s32;
    float d22 = s21*s21 + s22*s22;
    float d23 = s21*s31 + s22*s32;
    float d33 = s31*s31 + s32*s32;
    const float oneMG = 1.0f - GAMMA;   // -0.2
    float p1 = GAMMA*(q1h*d11 + q2h*d12 + q3h*d13) - oneMG*(sJ1*s11 + sJ2*s12);
    float p2 = GAMMA*(q1h*d12 + q2h*d22 + q3h*d23) - oneMG*(sJ1*s21 + sJ2*s22);
    float p3 = GAMMA*(q1h*d13 + q2h*d23 + q3h*d33) - oneMG*(sJ1*s31 + sJ2*s32);
    float muY2 = KAPPA * (YBAR - Y2);
    float muY3 = KAPPA * (YBAR - Y3);
    float r = RHO + GAMMA*(bq*(p1 - (Bc - Cc*q1)) - Cc*q1sq*d11 + muY2 + muY3)/c
                  - 1.32f*(sc1*sc1 + sc2*sc2)/(c*c);
    r = r / (1.0f - GAMMA*bq/c);
    float mu1 = r + p1 - (Bc - Cc*q1);
    float mu2 = r + p2 - Y2/q2;
    float mu3 = r + p3 - Y3/q3;
    float q1n = q1 * (1.0f + mu1*DT + s11*dZ1 + s12*dZ2);
    float q2n = q2 * (1.0f + mu2*DT + s21*dZ1 + s22*dZ2);
    float q3n = q3 * (1.0f + mu3*DT + s31*dZ1 + s32*dZ2);
    float Y2n = Y2 + muY2*DT + SIGMA*dZ1;
    float Y3n = Y3 + muY3*DT + SIGMA*dZ2;

    float qt1, qt2, qt3;
    net_eval(Y2n, Y3n, sIn, sAw, sB, sBW, colL, grp, bo_v,
             qt1,qt2,qt3, s11,s21,s31,s12,s22,s32);

    float e1 = q1n - qt1, e2 = q2n - qt2, e3 = q3n - qt3;
    loss += e1*e1 + e2*e2 + e3*e3;

    q1 = q1n; q2 = q2n; q3 = q3n; Y2 = Y2n; Y3 = Y3n;
  }

  loss *= valid * (1.0f / ((float)15000000));   // / (n * PERIOD)

  // --- block reduction -> one atomic per block ---
#pragma unroll
  for (int off = 32; off > 0; off >>= 1)
    loss += __shfl_down(loss, off, 64);
  __shared__ float sred[NB / 64];
  if (lane == 0) sred[wv] = loss;
  __syncthreads();
  if (threadIdx.x == 0){
    float s = 0.0f;
#pragma unroll
    for (int w = 0; w < NB / 64; ++w) s += sred[w];
    atomicAdd(out, s);
  }
}

extern "C" void kernel_launch(void* const* d_in, const int* in_sizes, int n_in,
                              void* d_out, int out_size, void* d_ws, size_t ws_size,
                              hipStream_t stream)
{
  const float* Y   = (const float*)d_in[0];
  const float* W0  = (const float*)d_in[1];
  const float* b0  = (const float*)d_in[2];
  const float* Wh1 = (const float*)d_in[3];
  const float* bh1 = (const float*)d_in[4];
  const float* Wo1 = (const float*)d_in[5];
  const float* bo1 = (const float*)d_in[6];
  const float* Wh2 = (const float*)d_in[7];
  const float* bh2 = (const float*)d_in[8];
  const float* Wo2 = (const float*)d_in[9];
  const float* bo2 = (const float*)d_in[10];
  const float* Wh3 = (const float*)d_in[11];
  const float* bh3 = (const float*)d_in[12];
  const float* Wo3 = (const float*)d_in[13];
  const float* bo3 = (const float*)d_in[14];

  const int n = in_sizes[0] / 2;

  hipMemsetAsync(d_out, 0, sizeof(float), stream);

  const int grid = (n + NB - 1) / NB;
  sim_kernel<<<grid, NB, 0, stream>>>(Y,
      W0, b0, Wh1, bh1, Wo1, bo1, Wh2, bh2, Wo2, bo2, Wh3, bh3, Wo3, bo3,
      (float*)d_out, n);
}